// Round 5
// baseline (781.669 us; speedup 1.0000x reference)
//
#include <hip/hip_runtime.h>
#include <hip/hip_bf16.h>
#include <cstdint>
#include <math.h>

// ---------------------------------------------------------------------------
// MultiHeadAttention: B=512, T=128, D=768, H=12, hd=64. fp32 in/out,
// bf16 MFMA compute.
//
// Stages:
//   1) cast x (fp32) -> bf16                     [M=65536 x 768]
//   2) transpose+cast Wq/Wk/Wv -> Wqkv^T bf16    [2304 x 768], Wo^T [768 x 768]
//   3) GEMM qkv = x * Wqkv   (bf16 out)          [65536 x 2304]   gemm_bk32
//   4) attention per (b,h); ctx overwrites Q region of qkv
//   5) GEMM out = ctx * Wo + bo (fp32 out)                        gemm_bk32
//
// gemm_bk32 (round 4/5): OCCUPANCY over schedule. Rounds 2-3 proved the
// 256x256 / 128KiB / 1-block-per-CU structure is convoy-bound (MfmaUtil
// stuck at 37-39% with 2 waves/SIMD and fully-serialized per-block
// head/tail, 9 blocks per CU). Geometry:
//   BM=128, BN=256, BK=32, wave-tile 64x64 (acc 4x4 = 64 VGPR),
//   512 thr = 8 waves (2M x 4N), 3-buffer LDS ring of 24 KiB = 72 KiB
//   -> 2 blocks/CU (147456 <= 163840), 4 waves/SIMD, 50% occupancy.
// Cross-block overlap hides prologue latency, barrier convoys and the
// epilogue. Kept from earlier rounds (all counter-verified): T1 XCD/panel
// swizzle (FETCH 877->210 MB), T2 LDS swizzle (conflicts 2.8e7->0),
// counted-vmcnt single-barrier phases, setprio, vectorized LDS epilogue.
//
// Ring ledger (phase t, buf rb=t%3, stage sb=(t+2)%3):
//   - RD(t) from buf rb: guaranteed resident by previous phase's
//     vmcnt(3)+barrier (outstanding there = stages of t+1,t+2 = 6 -> wait
//     until 3 left = tile t+1 landed; inductively tile t at this phase).
//   - STAGE(t+2) overwrites buf holding tile t-1, whose reads were issued
//     before barrier(t-1); gload data-return is >=200cy after issue, one
//     barrier + RD-block later. Same safety class as round-3 (verified).
//   - tail: t+2==NT -> vmcnt(0) (drain last stage); t+2>NT -> no wait.
// ---------------------------------------------------------------------------

typedef __bf16 bf16;
typedef __bf16 bf16x8 __attribute__((ext_vector_type(8)));
typedef float f32x4 __attribute__((ext_vector_type(4)));

#define MFMA16(a, b, c) __builtin_amdgcn_mfma_f32_16x16x32_bf16((a), (b), (c), 0, 0, 0)

// async global->LDS, 16B per lane; LDS dest = wave-uniform base + lane*16
#define GLD_LDS16(gp, lp)                                                       \
  __builtin_amdgcn_global_load_lds(                                             \
      (const __attribute__((address_space(1))) void*)(gp),                      \
      (__attribute__((address_space(3))) void*)(lp), 16, 0, 0)

// ---------------------------------------------------------------------------
// Stage 1: fp32 -> bf16 cast, 4 elems/thread
// ---------------------------------------------------------------------------
__global__ __launch_bounds__(256) void cast_x_bf16(const float* __restrict__ in,
                                                   bf16* __restrict__ out, int n) {
  int i = (blockIdx.x * 256 + threadIdx.x) * 4;
  if (i < n) {
    float4 v = *(const float4*)(in + i);
    bf16 o[4] = {(bf16)v.x, (bf16)v.y, (bf16)v.z, (bf16)v.w};
    *(uint2*)(out + i) = *(const uint2*)o;
  }
}

// ---------------------------------------------------------------------------
// Stage 2: 768x768 transpose + cast: Out[n][k] = W[k][n]
// ---------------------------------------------------------------------------
__global__ __launch_bounds__(256) void transpose_cast_w(const float* __restrict__ W,
                                                        bf16* __restrict__ Out) {
  __shared__ float t[32][33];
  int bx = blockIdx.x * 32;  // k tile
  int by = blockIdx.y * 32;  // n tile
  int tx = threadIdx.x, ty = threadIdx.y;  // block (32,8)
  for (int i = 0; i < 32; i += 8)
    t[ty + i][tx] = W[(size_t)(bx + ty + i) * 768 + by + tx];
  __syncthreads();
  for (int i = 0; i < 32; i += 8)
    Out[(size_t)(by + ty + i) * 768 + bx + tx] = (bf16)t[tx][ty + i];
}

// ---------------------------------------------------------------------------
// Stages 3/5: bf16 GEMM, C[M,N] = A[M,K] * Bt[N,K]^T.
// Requires M%128==0, N%256==0, K%32==0, K/32>=3, gridDim.x%8==0.
// Per-buffer layout (12288 bf16 = 24 KiB): A[128][32] @0, B[256][32] @4096.
// ---------------------------------------------------------------------------
template <bool OUT_F32>
__global__ __launch_bounds__(512, 4) void gemm_bk32(
    const bf16* __restrict__ A, int lda, const bf16* __restrict__ Bt, int ldb,
    void* __restrict__ Cout, int ldc, const float* __restrict__ bias, int K,
    int ntn) {
  __shared__ bf16 smem[3 * 12288];  // 73728 B -> 2 blocks/CU

  const int tid = threadIdx.x;
  const int lane = tid & 63;
  const int w = tid >> 6;

  // T1: nt-major within A-panel groups, XCD-chunked bijective swizzle.
  const int nwg = gridDim.x;
  const int wg = (blockIdx.x & 7) * (nwg >> 3) + (blockIdx.x >> 3);
  const int m0 = (wg / ntn) * 128;
  const int n0 = (wg % ntn) * 256;

  // Staging constants: panels [rows][32 k] at 64 B row stride; swizzle
  // phys_byte = logical ^ (((logical>>7)&3)<<4)  (row bits 1-2 -> bits 4-5).
  // Linear gload dest d = region + tid*16 -> row = tid>>2, src col
  // pre-swizzled per-thread constant c0.
  const int r0 = tid >> 2;
  const int c0 = ((((tid & 3) * 16) ^ (((tid >> 3) & 3) << 4)) >> 1);
  const bf16* As0 = A + (size_t)(m0 + r0) * lda + c0;         // A rows 0-127
  const bf16* Bs0 = Bt + (size_t)(n0 + r0) * ldb + c0;        // B rows 0-127
  const bf16* Bs1 = Bs0 + (size_t)128 * ldb;                  // B rows 128-255

  // Fragment-read constants (same swizzle; row bits 1-2 == lm bits 1-2).
  const int lm = lane & 15;
  const int kqs = ((lane >> 4) * 8) ^ (((lm >> 1) & 3) << 3);
  const int wm = (w & 1) * 64;    // wave M rows (2 groups x 64)
  const int wn = (w >> 1) * 64;   // wave N cols (4 groups x 64)
  const bf16* pA = smem + (wm + lm) * 32 + kqs;
  const bf16* pB = smem + 4096 + (wn + lm) * 32 + kqs;

  f32x4 acc[4][4];
#pragma unroll
  for (int i = 0; i < 4; ++i)
#pragma unroll
    for (int j = 0; j < 4; ++j) acc[i][j] = (f32x4){0.f, 0.f, 0.f, 0.f};

  const int NT = K >> 5;  // 24 for K=768

  auto STAGE = [&](int t, int sb) {
    const int k0 = t * 32;
    bf16* base = smem + sb * 12288;
    GLD_LDS16(As0 + k0, base + w * 512);           // A rows 0-127
    GLD_LDS16(Bs0 + k0, base + 4096 + w * 512);    // B rows 0-127
    GLD_LDS16(Bs1 + k0, base + 8192 + w * 512);    // B rows 128-255
  };

  // ---- prologue: tiles 0,1 staged; wait tile 0 (3 loads of tile 1 remain)
  STAGE(0, 0);
  STAGE(1, 1);
  asm volatile("s_waitcnt vmcnt(3)" ::: "memory");
  __builtin_amdgcn_s_barrier();
  __builtin_amdgcn_sched_barrier(0);

  int rb = 0, sb = 2;
  for (int t = 0; t < NT; ++t) {
    const bf16* a = pA + rb * 12288;
    const bf16* b = pB + rb * 12288;
    bf16x8 af[4], bfr[4];
#pragma unroll
    for (int mi = 0; mi < 4; ++mi) af[mi] = *(const bf16x8*)(a + mi * 512);
#pragma unroll
    for (int ni = 0; ni < 4; ++ni) bfr[ni] = *(const bf16x8*)(b + ni * 512);

    if (t + 2 < NT) STAGE(t + 2, sb);
    __builtin_amdgcn_sched_barrier(0);
    if (t + 2 < NT)
      asm volatile("s_waitcnt vmcnt(3)" ::: "memory");
    else if (t + 2 == NT)
      asm volatile("s_waitcnt vmcnt(0)" ::: "memory");
    __builtin_amdgcn_s_barrier();
    asm volatile("s_waitcnt lgkmcnt(0)" ::: "memory");
    __builtin_amdgcn_sched_barrier(0);

    __builtin_amdgcn_s_setprio(1);
#pragma unroll
    for (int mi = 0; mi < 4; ++mi)
#pragma unroll
      for (int ni = 0; ni < 4; ++ni)
        acc[mi][ni] = MFMA16(af[mi], bfr[ni], acc[mi][ni]);
    __builtin_amdgcn_s_setprio(0);

    rb = rb == 2 ? 0 : rb + 1;
    sb = sb == 2 ? 0 : sb + 1;
  }

  __syncthreads();  // all waves done with ring reads; LDS free for epilogue

  // ---- vectorized epilogue via LDS ----
  // C/D layout: col=lane&15, row=(lane>>4)*4+reg  [m89/m91]
  const int lr = (lane >> 4) * 4;
  if constexpr (!OUT_F32) {
    // bf16 C-tile [128][256] = 64 KiB, single pass. XOR row bits 2-3 into
    // byte bits 5-6 -> four 32B row-group segments in distinct slots.
#pragma unroll
    for (int mi = 0; mi < 4; ++mi)
#pragma unroll
      for (int ni = 0; ni < 4; ++ni) {
        const int colb = (wn + ni * 16 + lm) * 2;
#pragma unroll
        for (int r = 0; r < 4; ++r) {
          const int row = wm + mi * 16 + lr + r;
          const unsigned ad = ((unsigned)row * 512 + colb) ^ (((row >> 2) & 3) << 5);
          *(bf16*)((char*)smem + ad) = (bf16)acc[mi][ni][r];
        }
      }
    __syncthreads();
#pragma unroll
    for (int s = 0; s < 8; ++s) {
      const unsigned e = s * 8192 + tid * 16;
      const int row = e >> 9, col = (e & 511) >> 1;
      uint4 v = *(const uint4*)((char*)smem + (e ^ (((row >> 2) & 3) << 5)));
      *(uint4*)((bf16*)Cout + (size_t)(m0 + row) * ldc + n0 + col) = v;
    }
  } else {
    // fp32 in two 64-row halves: [64][256] f32 = 64 KiB each. XOR row bits
    // 2-3 into byte bits 6-7 (64B segments -> distinct slots).
#pragma unroll
    for (int h = 0; h < 2; ++h) {
      __syncthreads();
      if ((w & 1) == h) {
#pragma unroll
        for (int mi = 0; mi < 4; ++mi)
#pragma unroll
          for (int ni = 0; ni < 4; ++ni) {
            const int colb = (wn + ni * 16 + lm) * 4;
#pragma unroll
            for (int r = 0; r < 4; ++r) {
              const int row = mi * 16 + lr + r;  // 0..63 within half
              const unsigned ad =
                  ((unsigned)row * 1024 + colb) ^ (((row >> 2) & 3) << 6);
              *(float*)((char*)smem + ad) = acc[mi][ni][r];
            }
          }
      }
      __syncthreads();
#pragma unroll
      for (int s = 0; s < 8; ++s) {
        const unsigned e = s * 8192 + tid * 16;
        const int row = e >> 10, col = (e & 1023) >> 2;
        float4 v = *(const float4*)((char*)smem + (e ^ (((row >> 2) & 3) << 6)));
        float4 bb = *(const float4*)(bias + n0 + col);
        v.x += bb.x; v.y += bb.y; v.z += bb.z; v.w += bb.w;
        *(float4*)((float*)Cout + (size_t)(m0 + h * 64 + row) * ldc + n0 + col) = v;
      }
    }
  }
}

// ---------------------------------------------------------------------------
// Stage 4: attention, one block (256 thr, 4 waves) per (b,h). Q fragments
// loaded directly global->VGPR (read exactly once); LDS 52,224 B ->
// 3 blocks/CU; XCD-chunked block swizzle. (Unchanged from round 3.)
// ---------------------------------------------------------------------------
__global__ __launch_bounds__(256, 3) void attn_kernel(const bf16* __restrict__ qkv,
                                                      bf16* __restrict__ ctx) {
  constexpr int LDQ = 2304;
  constexpr int SKS = 72;   // sK row stride (64 cols + pad)
  constexpr int SPS = 136;  // sP/sVt row stride (128 cols + pad)
  __shared__ bf16 smem[26112];              // 52224 B
  bf16* sK = smem;                          // [128][72]  (aliases sP front)
  bf16* sP = smem;                          // [128][136] = 17408 elems
  bf16* sVt = smem + 17408;                 // [64][136]  Vt[d][t] = V[t][d]

  const int bh = (blockIdx.x & 7) * 768 + (blockIdx.x >> 3);
  const int b = bh / 12, h = bh % 12;
  const bf16* Qg = qkv + (size_t)b * 128 * LDQ + h * 64;
  const bf16* Kg = Qg + 768;
  const bf16* Vg = Qg + 1536;

  const int tid = threadIdx.x;
  const int lane = tid & 63;
  const int w = tid >> 6;      // wave handles rows w*32 .. w*32+31
  const int lm = lane & 15;
  const int kq = (lane >> 4) * 8;
  const int lr = (lane >> 4) * 4;

  // ---- hoisted Q fragment loads (global -> VGPR) ----
  bf16x8 aq[2][2];
#pragma unroll
  for (int mi = 0; mi < 2; ++mi)
#pragma unroll
    for (int kk2 = 0; kk2 < 2; ++kk2)
      aq[mi][kk2] = *(const bf16x8*)(Qg + (size_t)(w * 32 + mi * 16 + lm) * LDQ +
                                     kk2 * 32 + kq);

  // ---- stage K row-major; V transposed ----
  {
    int row = tid >> 1, half = tid & 1;
    const uint4* ksrc = (const uint4*)(Kg + (size_t)row * LDQ + half * 32);
    const uint4* vsrc = (const uint4*)(Vg + (size_t)row * LDQ + half * 32);
    uint4* kdst = (uint4*)(sK + row * SKS + half * 32);
    uint4 vt[4];
    for (int i = 0; i < 4; ++i) {
      kdst[i] = ksrc[i];
      vt[i] = vsrc[i];
    }
    const bf16* tp = (const bf16*)vt;
    for (int d = 0; d < 32; ++d) sVt[(half * 32 + d) * SPS + row] = tp[d];
  }
  __syncthreads();

  // ---- S = Q K^T ----
  f32x4 sacc[2][8];
  for (int i = 0; i < 2; ++i)
    for (int j = 0; j < 8; ++j) sacc[i][j] = (f32x4){0.f, 0.f, 0.f, 0.f};
  for (int kk2 = 0; kk2 < 2; ++kk2) {
    bf16x8 bk[8];
    for (int ni = 0; ni < 8; ++ni)
      bk[ni] = *(const bf16x8*)(sK + (ni * 16 + lm) * SKS + kk2 * 32 + kq);
    for (int mi = 0; mi < 2; ++mi)
      for (int ni = 0; ni < 8; ++ni)
        sacc[mi][ni] = MFMA16(aq[mi][kk2], bk[ni], sacc[mi][ni]);
  }

  // ---- causal softmax (scale=1/8) ----
  float inv[2][4];
  for (int mi = 0; mi < 2; ++mi) {
    for (int r = 0; r < 4; ++r) {
      int row = w * 32 + mi * 16 + lr + r;
      float vals[8];
      float mx = -INFINITY;
      for (int ni = 0; ni < 8; ++ni) {
        int col = ni * 16 + lm;
        float v = sacc[mi][ni][r] * 0.125f;
        if (col > row) v = -INFINITY;
        vals[ni] = v;
        mx = fmaxf(mx, v);
      }
      for (int off = 1; off < 16; off <<= 1) mx = fmaxf(mx, __shfl_xor(mx, off, 64));
      float sum = 0.f;
      for (int ni = 0; ni < 8; ++ni) {
        float p = __expf(vals[ni] - mx);  // exp(-inf)=0
        vals[ni] = p;
        sum += p;
      }
      for (int off = 1; off < 16; off <<= 1) sum += __shfl_xor(sum, off, 64);
      inv[mi][r] = 1.f / sum;
      for (int ni = 0; ni < 8; ++ni) sacc[mi][ni][r] = vals[ni];
    }
  }
  __syncthreads();  // all waves done reading sK before sP overwrites it

  // ---- write unnormalized P (bf16) to LDS ----
  for (int mi = 0; mi < 2; ++mi)
    for (int ni = 0; ni < 8; ++ni)
      for (int r = 0; r < 4; ++r) {
        int row = w * 32 + mi * 16 + lr + r;
        int col = ni * 16 + lm;
        sP[row * SPS + col] = (bf16)sacc[mi][ni][r];
      }
  __syncthreads();

  // ---- ctx = P * V ----
  f32x4 oacc[2][4];
  for (int i = 0; i < 2; ++i)
    for (int j = 0; j < 4; ++j) oacc[i][j] = (f32x4){0.f, 0.f, 0.f, 0.f};
  for (int kk = 0; kk < 128; kk += 32) {
    bf16x8 ap[2], bv[4];
    for (int mi = 0; mi < 2; ++mi)
      ap[mi] = *(const bf16x8*)(sP + (w * 32 + mi * 16 + lm) * SPS + kk + kq);
    for (int ci = 0; ci < 4; ++ci)
      bv[ci] = *(const bf16x8*)(sVt + (ci * 16 + lm) * SPS + kk + kq);
    for (int mi = 0; mi < 2; ++mi)
      for (int ci = 0; ci < 4; ++ci)
        oacc[mi][ci] = MFMA16(ap[mi], bv[ci], oacc[mi][ci]);
  }

  // ---- write ctx over the Q region ----
  bf16* Cg = ctx + (size_t)b * 128 * LDQ + h * 64;
  for (int mi = 0; mi < 2; ++mi)
    for (int ci = 0; ci < 4; ++ci)
      for (int r = 0; r < 4; ++r) {
        int row = w * 32 + mi * 16 + lr + r;
        int col = ci * 16 + lm;
        Cg[(size_t)row * LDQ + col] = (bf16)(oacc[mi][ci][r] * inv[mi][r]);
      }
}

// ---------------------------------------------------------------------------
extern "C" void kernel_launch(void* const* d_in, const int* in_sizes, int n_in,
                              void* d_out, int out_size, void* d_ws, size_t ws_size,
                              hipStream_t stream) {
  const float* x = (const float*)d_in[0];
  const float* Wq = (const float*)d_in[1];
  const float* Wk = (const float*)d_in[2];
  const float* Wv = (const float*)d_in[3];
  const float* Wo = (const float*)d_in[4];
  const float* bo = (const float*)d_in[5];
  float* out = (float*)d_out;

  constexpr int M = 512 * 128;      // 65536 tokens
  constexpr int D = 768;
  constexpr size_t XB_BYTES = (size_t)M * D * 2;            // 100663296
  constexpr size_t WQKV_BYTES = (size_t)3 * D * D * 2;      // 3538944
  constexpr size_t WOT_BYTES = (size_t)D * D * 2;           // 1179648

  char* ws = (char*)d_ws;
  bf16* xb = (bf16*)ws;
  bf16* wqkv = (bf16*)(ws + XB_BYTES);
  bf16* wot = (bf16*)(ws + XB_BYTES + WQKV_BYTES);
  bf16* qkv = (bf16*)(ws + XB_BYTES + WQKV_BYTES + WOT_BYTES);  // [M][2304]

  // 1) cast x
  cast_x_bf16<<<(M * D) / 1024, 256, 0, stream>>>(x, xb, M * D);
  // 2) weight transposes
  dim3 tb(32, 8);
  transpose_cast_w<<<dim3(24, 24), tb, 0, stream>>>(Wq, wqkv);
  transpose_cast_w<<<dim3(24, 24), tb, 0, stream>>>(Wk, wqkv + 768 * 768);
  transpose_cast_w<<<dim3(24, 24), tb, 0, stream>>>(Wv, wqkv + 2 * 768 * 768);
  transpose_cast_w<<<dim3(24, 24), tb, 0, stream>>>(Wo, wot);
  // 3) fused QKV GEMM: [65536 x 768] * [768 x 2304] -> bf16 [65536 x 2304]
  //    grid = 512 M-tiles x 9 N-tiles = 4608 (divisible by 8)
  gemm_bk32<false><<<dim3(4608), 512, 0, stream>>>(xb, 768, wqkv, 768, qkv,
                                                   2304, nullptr, 768, 9);
  // 4) attention; ctx written in-place over Q region of qkv
  attn_kernel<<<512 * 12, 256, 0, stream>>>(qkv, qkv);
  // 5) output GEMM: ctx [65536 x 768] (lda=2304) * Wo -> fp32 out + bias
  //    grid = 512 M-tiles x 3 N-tiles = 1536 (divisible by 8)
  gemm_bk32<true><<<dim3(1536), 512, 0, stream>>>(qkv, 2304, wot, 768, out, 768,
                                                  bo, 768, 3);
}

// Round 6
// 779.514 us; speedup vs baseline: 1.0028x; 1.0028x over previous
//
#include <hip/hip_runtime.h>
#include <hip/hip_bf16.h>
#include <cstdint>
#include <math.h>

// ---------------------------------------------------------------------------
// MultiHeadAttention: B=512, T=128, D=768, H=12, hd=64. fp32 in/out,
// bf16 MFMA compute.
//
// gemm256 (round 6): R3 base (256x256, BK=64, 8 waves 128x64, 8-phase,
// single barrier/phase — best measured 262 us) + REGISTER DOUBLE-BUFFERED
// FRAGMENTS. Rounds 1-5 invariant: MfmaUtil 36-39% across four structural
// changes, because each phase's MFMA depended on the ds_reads issued in the
// SAME phase -> LDS service (~715 cyc) + MFMA (~620 cyc/SIMD) serialized
// (1456 cyc/phase measured, 620/1456 = 42% ~= counter). Now phase p issues
// reads for phase p+1 into the alternate frag set (A: X/Y per phase,
// B: U/V per 2 phases); MFMA(p) consumes regs read at p-1 (complete).
// No lgkmcnt(0) asm: compiler dataflow waits only on the consumed set.
//
// Coverage rule: reads at phase p are guaranteed for stages <= the last
// vmcnt+barrier before p. vm(6) at EVERY even phase (outstanding there =
// last 3 stage-calls x 2 loads):
//   vm@ph2 covers <= prev-ph7; vm@ph4 <= ph1; vm@ph6 <= ph3; vm@ph8 <= ph5.
// Read sites (first read of each region) vs coverage:
//   b0k0(t2) read@ph8  <- staged ph2(A),ph3(B); vm@ph6 covers <=ph3  OK
//   b0k1(t2) read@ph2' <- staged ph4,ph5;       vm@ph8 covers <=ph5  OK
//   b1k0(t3) read@ph4' <- staged ph6,ph7;       vm@ph2' covers <=ph7 OK
//   b1k1(t3) read@ph6' <- staged ph8,ph1';      vm@ph4' covers <=ph1' OK
// WAR (stage vs last read of old content): b0k0 lastread ph1 -> staged
// ph2/3; b0k1 ph3 -> ph4/5; b1k0 ph5 -> ph6/7; b1k1 ph7 -> ph8/1'. All
// gaps >= 1 barrier + MFMA block vs ~200cy gload flight (R3-verified class).
// Prologue: 7 regions (b0 full + b1k0 + b1k1-A), vm(6); tail: vm(4)@ph2,
// vm(0)@ph4, then drained.
// ---------------------------------------------------------------------------

typedef __bf16 bf16;
typedef __bf16 bf16x8 __attribute__((ext_vector_type(8)));
typedef float f32x4 __attribute__((ext_vector_type(4)));

#define MFMA16(a, b, c) __builtin_amdgcn_mfma_f32_16x16x32_bf16((a), (b), (c), 0, 0, 0)

#define GLD_LDS16(gp, lp)                                                       \
  __builtin_amdgcn_global_load_lds(                                             \
      (const __attribute__((address_space(1))) void*)(gp),                      \
      (__attribute__((address_space(3))) void*)(lp), 16, 0, 0)

// ---------------------------------------------------------------------------
__global__ __launch_bounds__(256) void cast_x_bf16(const float* __restrict__ in,
                                                   bf16* __restrict__ out, int n) {
  int i = (blockIdx.x * 256 + threadIdx.x) * 4;
  if (i < n) {
    float4 v = *(const float4*)(in + i);
    bf16 o[4] = {(bf16)v.x, (bf16)v.y, (bf16)v.z, (bf16)v.w};
    *(uint2*)(out + i) = *(const uint2*)o;
  }
}

// ---------------------------------------------------------------------------
__global__ __launch_bounds__(256) void transpose_cast_w(const float* __restrict__ W,
                                                        bf16* __restrict__ Out) {
  __shared__ float t[32][33];
  int bx = blockIdx.x * 32;
  int by = blockIdx.y * 32;
  int tx = threadIdx.x, ty = threadIdx.y;
  for (int i = 0; i < 32; i += 8)
    t[ty + i][tx] = W[(size_t)(bx + ty + i) * 768 + by + tx];
  __syncthreads();
  for (int i = 0; i < 32; i += 8)
    Out[(size_t)(by + ty + i) * 768 + bx + tx] = (bf16)t[tx][ty + i];
}

// ---------------------------------------------------------------------------
// Stages 3/5: bf16 GEMM, C[M,N] = A[M,K] * Bt[N,K]^T.
// Requires M%256==0, N%256==0, K%64==0, K/64 even and >=4, gridDim.x%8==0.
// ---------------------------------------------------------------------------
template <bool OUT_F32>
__global__ __launch_bounds__(512, 2) void gemm256(
    const bf16* __restrict__ A, int lda, const bf16* __restrict__ Bt, int ldb,
    void* __restrict__ Cout, int ldc, const float* __restrict__ bias, int K,
    int ntn) {
  // 2 buffers x 32768 elems; per buffer: A_k0 @0, A_k1 @8192, B_k0 @16384,
  // B_k1 @24576 (each 8192 elems = 16 KiB).
  __shared__ bf16 smem[2 * 32768];  // 131072 B

  const int tid = threadIdx.x;
  const int lane = tid & 63;
  const int w = tid >> 6;

  const int nwg = gridDim.x;
  const int wg = (blockIdx.x & 7) * (nwg >> 3) + (blockIdx.x >> 3);
  const int m0 = (wg / ntn) * 256;
  const int n0 = (wg % ntn) * 256;

  // staging: per-panel [256 rows][32 k], 64 B row stride, swizzle
  // phys = logical ^ (((logical>>7)&3)<<4); linear gload dest, pre-swizzled src
  const int r0 = tid >> 2;
  const int c0 = ((((tid & 3) * 16) ^ (((tid >> 3) & 3) << 4)) >> 1);
  const bf16* As0 = A + (size_t)(m0 + r0) * lda + c0;
  const bf16* As1 = As0 + (size_t)128 * lda;
  const bf16* Bs0 = Bt + (size_t)(n0 + r0) * ldb + c0;
  const bf16* Bs1 = Bs0 + (size_t)128 * ldb;

  const int lm = lane & 15;
  const int kqs = ((lane >> 4) * 8) ^ (((lm >> 1) & 3) << 3);
  const int wm = (w & 1) * 128;
  const int wn = (w >> 1) * 64;
  const bf16* pA = smem + (wm + lm) * 32 + kqs;
  const bf16* pB = smem + 16384 + (wn + lm) * 32 + kqs;

  f32x4 acc[8][4];
#pragma unroll
  for (int i = 0; i < 8; ++i)
#pragma unroll
    for (int j = 0; j < 4; ++j) acc[i][j] = (f32x4){0.f, 0.f, 0.f, 0.f};

  // double-buffered fragment sets: A alternates X/Y, B alternates U/V
  bf16x8 afX[4], afY[4], bfU[4], bfV[4];

  const int NT = K >> 6;   // 12 for K=768
  const int NH = NT >> 1;  // 6

  auto SA = [&](int t, int kh) {
    const int ko = t * 64 + kh * 32;
    const int lo = (t & 1) * 32768 + kh * 8192;
    GLD_LDS16(As0 + ko, smem + lo + w * 512);
    GLD_LDS16(As1 + ko, smem + lo + 4096 + w * 512);
  };
  auto SB = [&](int t, int kh) {
    const int ko = t * 64 + kh * 32;
    const int lo = (t & 1) * 32768 + 16384 + kh * 8192;
    GLD_LDS16(Bs0 + ko, smem + lo + w * 512);
    GLD_LDS16(Bs1 + ko, smem + lo + 4096 + w * 512);
  };
  auto rdA = [&](bf16x8* d, int buf, int kh, int h) {
    const bf16* a = pA + buf * 32768 + kh * 8192 + h * 2048;
#pragma unroll
    for (int j = 0; j < 4; ++j) d[j] = *(const bf16x8*)(a + j * 512);
  };
  auto rdB = [&](bf16x8* d, int buf, int kh) {
    const bf16* b = pB + buf * 32768 + kh * 8192;
#pragma unroll
    for (int j = 0; j < 4; ++j) d[j] = *(const bf16x8*)(b + j * 512);
  };
  auto BAR = [&](int vm) {
    __builtin_amdgcn_sched_barrier(0);
    if (vm == 6) asm volatile("s_waitcnt vmcnt(6)" ::: "memory");
    else if (vm == 4) asm volatile("s_waitcnt vmcnt(4)" ::: "memory");
    else if (vm == 0) asm volatile("s_waitcnt vmcnt(0)" ::: "memory");
    __builtin_amdgcn_s_barrier();
    __builtin_amdgcn_sched_barrier(0);
  };
  auto MM = [&](bf16x8* a, bf16x8* b, int h) {
    __builtin_amdgcn_s_setprio(1);
#pragma unroll
    for (int j = 0; j < 4; ++j)
#pragma unroll
      for (int n = 0; n < 4; ++n)
        acc[h * 4 + j][n] = MFMA16(a[j], b[n], acc[h * 4 + j][n]);
    __builtin_amdgcn_s_setprio(0);
  };

  // ---- prologue: b0 full (tile 0) + b1k0 + b1k1-A (tile 1); B1k1 at ph1 ----
  SA(0, 0); SB(0, 0); SA(0, 1); SB(0, 1);
  SA(1, 0); SB(1, 0); SA(1, 1);
  asm volatile("s_waitcnt vmcnt(6)" ::: "memory");
  __builtin_amdgcn_s_barrier();
  __builtin_amdgcn_sched_barrier(0);
  // initial fragment loads for ph1 (consumed after next barrier)
  rdA(afX, 0, 0, 0);
  rdB(bfU, 0, 0);

  for (int i = 0; i < NH - 1; ++i) {
    const int t1 = 2 * i + 1, t2 = 2 * i + 2, t3 = 2 * i + 3;
    /*ph1*/ rdA(afY, 0, 0, 1);                   SB(t1, 1); BAR(-1); MM(afX, bfU, 0);
    /*ph2*/ rdA(afX, 0, 1, 0); rdB(bfV, 0, 1);   SA(t2, 0); BAR(6);  MM(afY, bfU, 1);
    /*ph3*/ rdA(afY, 0, 1, 1);                   SB(t2, 0); BAR(-1); MM(afX, bfV, 0);
    /*ph4*/ rdA(afX, 1, 0, 0); rdB(bfU, 1, 0);   SA(t2, 1); BAR(6);  MM(afY, bfV, 1);
    /*ph5*/ rdA(afY, 1, 0, 1);                   SB(t2, 1); BAR(-1); MM(afX, bfU, 0);
    /*ph6*/ rdA(afX, 1, 1, 0); rdB(bfV, 1, 1);   SA(t3, 0); BAR(6);  MM(afY, bfU, 1);
    /*ph7*/ rdA(afY, 1, 1, 1);                   SB(t3, 0); BAR(-1); MM(afX, bfV, 0);
    /*ph8*/ rdA(afX, 0, 0, 0); rdB(bfU, 0, 0);   SA(t3, 1); BAR(6);  MM(afY, bfV, 1);
  }
  // ---- final iteration (tiles NT-2, NT-1): only SB(NT-1,1) remains ----
  {
    const int t1 = NT - 1;
    /*ph1*/ rdA(afY, 0, 0, 1);                   SB(t1, 1); BAR(-1); MM(afX, bfU, 0);
    /*ph2*/ rdA(afX, 0, 1, 0); rdB(bfV, 0, 1);              BAR(4);  MM(afY, bfU, 1);
    /*ph3*/ rdA(afY, 0, 1, 1);                              BAR(-1); MM(afX, bfV, 0);
    /*ph4*/ rdA(afX, 1, 0, 0); rdB(bfU, 1, 0);              BAR(0);  MM(afY, bfV, 1);
    /*ph5*/ rdA(afY, 1, 0, 1);                              BAR(-1); MM(afX, bfU, 0);
    /*ph6*/ rdA(afX, 1, 1, 0); rdB(bfV, 1, 1);              BAR(-1); MM(afY, bfU, 1);
    /*ph7*/ rdA(afY, 1, 1, 1);                              BAR(-1); MM(afX, bfV, 0);
    /*ph8*/                                                 BAR(-1); MM(afY, bfV, 1);
  }

  __syncthreads();  // all staging landed (vm(0) at final ph4), LDS free

  // ---- vectorized epilogue via LDS (R3-verified) ----
  // C/D layout: col=lane&15, row=(lane>>4)*4+reg  [m89/m91]
  const int lr = (lane >> 4) * 4;
  if constexpr (!OUT_F32) {
    const unsigned exw = (unsigned)(lane >> 4) << 5;
#pragma unroll
    for (int mi = 0; mi < 8; ++mi)
#pragma unroll
      for (int ni = 0; ni < 4; ++ni) {
        const int colb = (wn + ni * 16 + lm) * 2;
#pragma unroll
        for (int r = 0; r < 4; ++r) {
          const unsigned ad = (unsigned)(wm + mi * 16 + lr + r) * 512 + colb;
          *(bf16*)((char*)smem + (ad ^ exw)) = (bf16)acc[mi][ni][r];
        }
      }
    __syncthreads();
    const unsigned exr = (unsigned)((tid >> 7) & 3) << 5;
#pragma unroll
    for (int s = 0; s < 16; ++s) {
      const int e = s * 4096 + tid * 8;
      const int row = e >> 8, col = e & 255;
      uint4 v = *(const uint4*)((char*)smem + (((unsigned)row * 512 + col * 2) ^ exr));
      *(uint4*)((bf16*)Cout + (size_t)(m0 + row) * ldc + n0 + col) = v;
    }
  } else {
    const unsigned exw = (unsigned)(lane >> 4) << 6;
#pragma unroll
    for (int h = 0; h < 2; ++h) {
      __syncthreads();
      if ((w & 1) == h) {
#pragma unroll
        for (int mi = 0; mi < 8; ++mi)
#pragma unroll
          for (int ni = 0; ni < 4; ++ni) {
            const int colb = (wn + ni * 16 + lm) * 4;
#pragma unroll
            for (int r = 0; r < 4; ++r) {
              const unsigned ad = (unsigned)(mi * 16 + lr + r) * 1024 + colb;
              *(float*)((char*)smem + (ad ^ exw)) = acc[mi][ni][r];
            }
          }
      }
      __syncthreads();
#pragma unroll
      for (int s = 0; s < 16; ++s) {
        const int row = s * 8 + w;
        const int col = (lane & 63) * 4;
        const unsigned xr = (unsigned)((row >> 2) & 3) << 6;
        float4 v = *(const float4*)((char*)smem + (((unsigned)row * 1024 + col * 4) ^ xr));
        float4 bb = *(const float4*)(bias + n0 + col);
        v.x += bb.x; v.y += bb.y; v.z += bb.z; v.w += bb.w;
        *(float4*)((float*)Cout + (size_t)(m0 + h * 128 + row) * ldc + n0 + col) = v;
      }
    }
  }
}

// ---------------------------------------------------------------------------
// Stage 4: attention (unchanged from R3/R5): one block (256 thr, 4 waves)
// per (b,h); Q direct global->VGPR; LDS 52,224 B -> 3 blocks/CU; XCD swizzle.
// ---------------------------------------------------------------------------
__global__ __launch_bounds__(256, 3) void attn_kernel(const bf16* __restrict__ qkv,
                                                      bf16* __restrict__ ctx) {
  constexpr int LDQ = 2304;
  constexpr int SKS = 72;
  constexpr int SPS = 136;
  __shared__ bf16 smem[26112];
  bf16* sK = smem;
  bf16* sP = smem;
  bf16* sVt = smem + 17408;

  const int bh = (blockIdx.x & 7) * 768 + (blockIdx.x >> 3);
  const int b = bh / 12, h = bh % 12;
  const bf16* Qg = qkv + (size_t)b * 128 * LDQ + h * 64;
  const bf16* Kg = Qg + 768;
  const bf16* Vg = Qg + 1536;

  const int tid = threadIdx.x;
  const int lane = tid & 63;
  const int w = tid >> 6;
  const int lm = lane & 15;
  const int kq = (lane >> 4) * 8;
  const int lr = (lane >> 4) * 4;

  bf16x8 aq[2][2];
#pragma unroll
  for (int mi = 0; mi < 2; ++mi)
#pragma unroll
    for (int kk2 = 0; kk2 < 2; ++kk2)
      aq[mi][kk2] = *(const bf16x8*)(Qg + (size_t)(w * 32 + mi * 16 + lm) * LDQ +
                                     kk2 * 32 + kq);

  {
    int row = tid >> 1, half = tid & 1;
    const uint4* ksrc = (const uint4*)(Kg + (size_t)row * LDQ + half * 32);
    const uint4* vsrc = (const uint4*)(Vg + (size_t)row * LDQ + half * 32);
    uint4* kdst = (uint4*)(sK + row * SKS + half * 32);
    uint4 vt[4];
    for (int i = 0; i < 4; ++i) {
      kdst[i] = ksrc[i];
      vt[i] = vsrc[i];
    }
    const bf16* tp = (const bf16*)vt;
    for (int d = 0; d < 32; ++d) sVt[(half * 32 + d) * SPS + row] = tp[d];
  }
  __syncthreads();

  f32x4 sacc[2][8];
  for (int i = 0; i < 2; ++i)
    for (int j = 0; j < 8; ++j) sacc[i][j] = (f32x4){0.f, 0.f, 0.f, 0.f};
  for (int kk2 = 0; kk2 < 2; ++kk2) {
    bf16x8 bk[8];
    for (int ni = 0; ni < 8; ++ni)
      bk[ni] = *(const bf16x8*)(sK + (ni * 16 + lm) * SKS + kk2 * 32 + kq);
    for (int mi = 0; mi < 2; ++mi)
      for (int ni = 0; ni < 8; ++ni)
        sacc[mi][ni] = MFMA16(aq[mi][kk2], bk[ni], sacc[mi][ni]);
  }

  float inv[2][4];
  for (int mi = 0; mi < 2; ++mi) {
    for (int r = 0; r < 4; ++r) {
      int row = w * 32 + mi * 16 + lr + r;
      float vals[8];
      float mx = -INFINITY;
      for (int ni = 0; ni < 8; ++ni) {
        int col = ni * 16 + lm;
        float v = sacc[mi][ni][r] * 0.125f;
        if (col > row) v = -INFINITY;
        vals[ni] = v;
        mx = fmaxf(mx, v);
      }
      for (int off = 1; off < 16; off <<= 1) mx = fmaxf(mx, __shfl_xor(mx, off, 64));
      float sum = 0.f;
      for (int ni = 0; ni < 8; ++ni) {
        float p = __expf(vals[ni] - mx);
        vals[ni] = p;
        sum += p;
      }
      for (int off = 1; off < 16; off <<= 1) sum += __shfl_xor(sum, off, 64);
      inv[mi][r] = 1.f / sum;
      for (int ni = 0; ni < 8; ++ni) sacc[mi][ni][r] = vals[ni];
    }
  }
  __syncthreads();

  for (int mi = 0; mi < 2; ++mi)
    for (int ni = 0; ni < 8; ++ni)
      for (int r = 0; r < 4; ++r) {
        int row = w * 32 + mi * 16 + lr + r;
        int col = ni * 16 + lm;
        sP[row * SPS + col] = (bf16)sacc[mi][ni][r];
      }
  __syncthreads();

  f32x4 oacc[2][4];
  for (int i = 0; i < 2; ++i)
    for (int j = 0; j < 4; ++j) oacc[i][j] = (f32x4){0.f, 0.f, 0.f, 0.f};
  for (int kk = 0; kk < 128; kk += 32) {
    bf16x8 ap[2], bv[4];
    for (int mi = 0; mi < 2; ++mi)
      ap[mi] = *(const bf16x8*)(sP + (w * 32 + mi * 16 + lm) * SPS + kk + kq);
    for (int ci = 0; ci < 4; ++ci)
      bv[ci] = *(const bf16x8*)(sVt + (ci * 16 + lm) * SPS + kk + kq);
    for (int mi = 0; mi < 2; ++mi)
      for (int ci = 0; ci < 4; ++ci)
        oacc[mi][ci] = MFMA16(ap[mi], bv[ci], oacc[mi][ci]);
  }

  bf16* Cg = ctx + (size_t)b * 128 * LDQ + h * 64;
  for (int mi = 0; mi < 2; ++mi)
    for (int ci = 0; ci < 4; ++ci)
      for (int r = 0; r < 4; ++r) {
        int row = w * 32 + mi * 16 + lr + r;
        int col = ci * 16 + lm;
        Cg[(size_t)row * LDQ + col] = (bf16)(oacc[mi][ci][r] * inv[mi][r]);
      }
}

// ---------------------------------------------------------------------------
extern "C" void kernel_launch(void* const* d_in, const int* in_sizes, int n_in,
                              void* d_out, int out_size, void* d_ws, size_t ws_size,
                              hipStream_t stream) {
  const float* x = (const float*)d_in[0];
  const float* Wq = (const float*)d_in[1];
  const float* Wk = (const float*)d_in[2];
  const float* Wv = (const float*)d_in[3];
  const float* Wo = (const float*)d_in[4];
  const float* bo = (const float*)d_in[5];
  float* out = (float*)d_out;

  constexpr int M = 512 * 128;
  constexpr int D = 768;
  constexpr size_t XB_BYTES = (size_t)M * D * 2;
  constexpr size_t WQKV_BYTES = (size_t)3 * D * D * 2;
  constexpr size_t WOT_BYTES = (size_t)D * D * 2;

  char* ws = (char*)d_ws;
  bf16* xb = (bf16*)ws;
  bf16* wqkv = (bf16*)(ws + XB_BYTES);
  bf16* wot = (bf16*)(ws + XB_BYTES + WQKV_BYTES);
  bf16* qkv = (bf16*)(ws + XB_BYTES + WQKV_BYTES + WOT_BYTES);

  cast_x_bf16<<<(M * D) / 1024, 256, 0, stream>>>(x, xb, M * D);
  dim3 tb(32, 8);
  transpose_cast_w<<<dim3(24, 24), tb, 0, stream>>>(Wq, wqkv);
  transpose_cast_w<<<dim3(24, 24), tb, 0, stream>>>(Wk, wqkv + 768 * 768);
  transpose_cast_w<<<dim3(24, 24), tb, 0, stream>>>(Wv, wqkv + 2 * 768 * 768);
  transpose_cast_w<<<dim3(24, 24), tb, 0, stream>>>(Wo, wot);
  gemm256<false><<<dim3(2304), 512, 0, stream>>>(xb, 768, wqkv, 768, qkv, 2304,
                                                 nullptr, 768, 9);
  attn_kernel<<<512 * 12, 256, 0, stream>>>(qkv, qkv);
  gemm256<true><<<dim3(768), 512, 0, stream>>>(qkv, 2304, wot, 768, out, 768,
                                               bo, 768, 3);
}